// Round 2
// baseline (85.100 us; speedup 1.0000x reference)
//
#include <hip/hip_runtime.h>

// TT-embedding: VOC = 100*100*100, EMB = 4*4*8, RANK = 16, PAD_IDX = 0.
// core0 [1,100,4,16], core1 [16,100,4,16], core2 [16,100,8,1]  (float32)
// x [64,512] int32 indices; out [64,512,128] float32.
//
// v3: contraction reorder (A*B) then (AB)*C — 6144 MAC/token vs 10240.
//   stage1: AB[j1,j2,r2] = sum_r1 A[j1,r1]*B[r1,j2,r2]
//           lane = j2*16+r2 -> B column reads are stride-1 coalesced dwords,
//           A(i1) is wave-uniform -> SMEM/SGPR operands. 64 FMA/lane, 0 LDS.
//   AB bounce through LDS: 4x ds_write_b32 (conflict-free) + 4x ds_read_b128
//           (j1-stride padded 64->68 floats: start banks {4j1+16j2+4k}%32 are
//            2-way max -> free). 8 DS instr/wave total (v2 had 18).
//   stage2: out[j1,j2,j3] = sum_r2 AB[j1,j2,r2]*C[r2,j3]; lane does outputs
//           e0=2*lane,e0+1 -> 32 FMA; C loads are 16x dwordx2 (L1/L2-hot).

#define AB_STRIDE 68                     // 64 + 4 pad (floats)
#define LDS_PER_WAVE (4 * AB_STRIDE)     // 272 floats = 1088 B per wave

__global__ __launch_bounds__(256) void tt_embed_kernel(
    const int* __restrict__ x,
    const float* __restrict__ c0,   // [100,4,16]
    const float* __restrict__ c1,   // [16,100,4,16]
    const float* __restrict__ c2,   // [16,100,8]
    float* __restrict__ out,        // [nTok,128]
    int nTok)
{
    __shared__ __align__(16) float lds[4 * LDS_PER_WAVE];   // 4.25 KiB / block
    const int wave = threadIdx.x >> 6;
    const int lane = threadIdx.x & 63;
    const int t = blockIdx.x * 4 + wave;
    const bool active = (t < nTok);

    float* ABs = lds + wave * LDS_PER_WAVE;

    int idx = 0;
    if (active) idx = x[t];
    // Wave-uniform by construction; make it provably so -> SGPR -> scalar loads.
    idx = __builtin_amdgcn_readfirstlane(idx);
    const int i1 = idx / 10000;
    const int rem = idx - i1 * 10000;
    const int i2 = rem / 100;
    const int i3 = rem - i2 * 100;

    // ---- Stage 1: lane owns (j2 = lane>>4, r2 = lane&15), i.e. column `lane`
    // of B(i2) viewed as [r1, 64]. AB[j1] = sum_r1 A[j1,r1] * B[r1, lane].
    const float* cA = c0 + i1 * 64;          // uniform -> scalar loads
    const float* Bb = c1 + i2 * 64 + lane;   // per-lane; +r1*6400 floats per row

    float ab0 = 0.f, ab1 = 0.f, ab2 = 0.f, ab3 = 0.f;
    #pragma unroll
    for (int r1 = 0; r1 < 16; ++r1) {
        const float b = Bb[r1 * 6400];       // coalesced 256B per instruction
        ab0 += cA[r1]      * b;              // SGPR * VGPR fma
        ab1 += cA[16 + r1] * b;
        ab2 += cA[32 + r1] * b;
        ab3 += cA[48 + r1] * b;
    }

    // AB -> LDS, layout [j1][j2*16+r2] with j1-stride 68 (pad).
    ABs[0 * AB_STRIDE + lane] = ab0;         // 4x ds_write_b32, consecutive -> free
    ABs[1 * AB_STRIDE + lane] = ab1;
    ABs[2 * AB_STRIDE + lane] = ab2;
    ABs[3 * AB_STRIDE + lane] = ab3;

    // ---- C loads (VMEM, independent of LDS — issue while LDS drains)
    // Output pair e0=2*lane: j1w=lane>>4, j2w=(lane>>2)&3, j3=2*(lane&3).
    const int j3 = (lane & 3) * 2;
    const float* Cb = c2 + i3 * 8 + j3;      // + r2*800 floats per row
    float cvx[16], cvy[16];
    #pragma unroll
    for (int r2 = 0; r2 < 16; ++r2) {
        const float2 cv = *(const float2*)(Cb + r2 * 800);
        cvx[r2] = cv.x; cvy[r2] = cv.y;
    }

    // Ms is wave-private, lanes lockstep: drain LDS writes, fence compiler.
    asm volatile("s_waitcnt lgkmcnt(0)" ::: "memory");

    // ---- Stage 2: read AB[j1w, j2w, 0..15] (4x b128, 2-way banks, quad-broadcast)
    const int j1w = lane >> 4;
    const int j2w = (lane >> 2) & 3;
    const float4* abp = (const float4*)(ABs + j1w * AB_STRIDE + j2w * 16);
    float4 q0 = abp[0], q1 = abp[1], q2 = abp[2], q3 = abp[3];
    float ab[16] = { q0.x,q0.y,q0.z,q0.w, q1.x,q1.y,q1.z,q1.w,
                     q2.x,q2.y,q2.z,q2.w, q3.x,q3.y,q3.z,q3.w };

    float o0 = 0.f, o1 = 0.f;
    #pragma unroll
    for (int r2 = 0; r2 < 16; ++r2) {
        o0 += ab[r2] * cvx[r2];
        o1 += ab[r2] * cvy[r2];
    }

    if (idx == 0) { o0 = 0.f; o1 = 0.f; }    // PAD_IDX -> zero row

    if (active) {
        const int e0 = lane * 2;
        *(float2*)(out + (long)t * 128 + e0) = make_float2(o0, o1);
    }
}

extern "C" void kernel_launch(void* const* d_in, const int* in_sizes, int n_in,
                              void* d_out, int out_size, void* d_ws, size_t ws_size,
                              hipStream_t stream) {
    const int*   x  = (const int*)d_in[0];
    const float* c0 = (const float*)d_in[1];
    const float* c1 = (const float*)d_in[2];
    const float* c2 = (const float*)d_in[3];
    float* out = (float*)d_out;

    const int nTok = out_size / 128;           // 64*512 = 32768
    const int blocks = (nTok + 3) / 4;         // one wave per token, 4 waves/block
    tt_embed_kernel<<<dim3(blocks), dim3(256), 0, stream>>>(x, c0, c1, c2, out, nTok);
}

// Round 3
// 77.673 us; speedup vs baseline: 1.0956x; 1.0956x over previous
//
#include <hip/hip_runtime.h>

// TT-embedding: VOC = 100*100*100, EMB = 4*4*8, RANK = 16, PAD_IDX = 0.
// core0 [1,100,4,16], core1 [16,100,4,16], core2 [16,100,8,1]  (float32)
// x [64,512] int32 indices; out [64,512,128] float32.
//
// v4: (A*B)*C factoring (6144 MAC/token), ZERO LDS.
//   lane = j2*16 + r2.
//   stage1: AB[j1] = sum_r1 A[j1,r1]*B[r1,j2,r2]
//     - A(i1) uniform -> s_load (64 SGPR floats)
//     - B reads coalesced: c1 + r1*6400 + i2*64 + lane (16x 256B dword loads)
//   C: lane's row r2 is CONTIGUOUS: c2[(r2*100+i3)*8 + 0..7] -> 2x dwordx4
//     (v3's flaw: 16 loads with 4 unique addrs each; now 2 loads, 32B/lane)
//   stage2: p[j1*8+j3] = AB[j1]*C[r2,j3]; reduce over the 16-lane r2 group by
//     recursive halving (shfl_xor 8,4,2,1; vector 32->16->8->4->2):
//     30 shfl + 30 add + selects, all VALU/DPP -- no DS pipe, no fences.
//   Final: lane holds out[j1 = s0*2+s1, j2 = lane>>4, j3 = s2*4+s3*2 +{0,1}].
//
// Per-wave pipes: 20 VMEM, 0 DS, ~220 VALU (v3: 34 VMEM, 8 DS; v2: 10 VMEM, 18 DS).

__global__ __launch_bounds__(256) void tt_embed_kernel(
    const int* __restrict__ x,
    const float* __restrict__ c0,   // [100,4,16]
    const float* __restrict__ c1,   // [16,100,4,16]
    const float* __restrict__ c2,   // [16,100,8]
    float* __restrict__ out,        // [nTok,128]
    int nTok)
{
    const int wave = threadIdx.x >> 6;
    const int lane = threadIdx.x & 63;
    const int t = blockIdx.x * 4 + wave;
    const bool active = (t < nTok);

    int idx = 0;
    if (active) idx = x[t];
    // Wave-uniform -> SGPR -> scalar A loads, scalar-foldable addresses.
    idx = __builtin_amdgcn_readfirstlane(idx);
    const int i1 = idx / 10000;
    const int rem = idx - i1 * 10000;
    const int i2 = rem / 100;
    const int i3 = rem - i2 * 100;

    const int r2 = lane & 15;            // lane = j2*16 + r2

    // ---- C row for this lane: contiguous 32 B (issue early, independent)
    const float4* Cp = (const float4*)(c2 + (r2 * 100 + i3) * 8);
    float4 cl = Cp[0], ch = Cp[1];

    // ---- Stage 1: AB[j1] = sum_r1 A[j1,r1] * B[r1, lane]
    const float* cA = c0 + i1 * 64;      // uniform -> s_load
    const float* Bb = c1 + i2 * 64 + lane;

    float ab0 = 0.f, ab1 = 0.f, ab2 = 0.f, ab3 = 0.f;
    #pragma unroll
    for (int r1 = 0; r1 < 16; ++r1) {
        const float b = Bb[r1 * 6400];   // coalesced 256 B / instruction
        ab0 += cA[r1]      * b;          // SGPR * VGPR fma
        ab1 += cA[16 + r1] * b;
        ab2 += cA[32 + r1] * b;
        ab3 += cA[48 + r1] * b;
    }

    // ---- Products p[j1*8 + j3] = AB[j1] * C[r2, j3]
    const float ab[4] = { ab0, ab1, ab2, ab3 };
    const float cr[8] = { cl.x, cl.y, cl.z, cl.w, ch.x, ch.y, ch.z, ch.w };
    float p[32];
    #pragma unroll
    for (int a = 0; a < 4; ++a)
        #pragma unroll
        for (int j = 0; j < 8; ++j)
            p[a * 8 + j] = ab[a] * cr[j];

    // ---- Reduce-scatter over the 16-lane r2 group (recursive halving).
    // Round 0, xor 8: split j1 MSB. Lane keeps half selected by its own bit.
    const bool s0 = (lane >> 3) & 1;
    float q[16];
    #pragma unroll
    for (int k = 0; k < 16; ++k) {
        const float send = s0 ? p[k] : p[k + 16];
        const float keep = s0 ? p[k + 16] : p[k];
        q[k] = keep + __shfl_xor(send, 8);
    }
    // Round 1, xor 4: split j1 LSB.
    const bool s1 = (lane >> 2) & 1;
    float r_[8];
    #pragma unroll
    for (int k = 0; k < 8; ++k) {
        const float send = s1 ? q[k] : q[k + 8];
        const float keep = s1 ? q[k + 8] : q[k];
        r_[k] = keep + __shfl_xor(send, 4);
    }
    // Round 2, xor 2: split j3 bit2.
    const bool s2 = (lane >> 1) & 1;
    float s_[4];
    #pragma unroll
    for (int k = 0; k < 4; ++k) {
        const float send = s2 ? r_[k] : r_[k + 4];
        const float keep = s2 ? r_[k + 4] : r_[k];
        s_[k] = keep + __shfl_xor(send, 2);
    }
    // Round 3, xor 1: split j3 bit1. Lane ends with j3 pair {j3, j3+1}.
    const bool s3 = lane & 1;
    float o0, o1;
    {
        const float send0 = s3 ? s_[0] : s_[2];
        const float keep0 = s3 ? s_[2] : s_[0];
        o0 = keep0 + __shfl_xor(send0, 1);
        const float send1 = s3 ? s_[1] : s_[3];
        const float keep1 = s3 ? s_[3] : s_[1];
        o1 = keep1 + __shfl_xor(send1, 1);
    }

    if (idx == 0) { o0 = 0.f; o1 = 0.f; }   // PAD_IDX -> zero row

    if (active) {
        const int j1 = (int)s0 * 2 + (int)s1;
        const int j3 = (int)s2 * 4 + (int)s3 * 2;
        const int j2 = lane >> 4;
        const int e  = j1 * 32 + j2 * 8 + j3;
        *(float2*)(out + (long)t * 128 + e) = make_float2(o0, o1);
    }
}

extern "C" void kernel_launch(void* const* d_in, const int* in_sizes, int n_in,
                              void* d_out, int out_size, void* d_ws, size_t ws_size,
                              hipStream_t stream) {
    const int*   x  = (const int*)d_in[0];
    const float* c0 = (const float*)d_in[1];
    const float* c1 = (const float*)d_in[2];
    const float* c2 = (const float*)d_in[3];
    float* out = (float*)d_out;

    const int nTok = out_size / 128;           // 64*512 = 32768
    const int blocks = (nTok + 3) / 4;         // one wave per token, 4 waves/block
    tt_embed_kernel<<<dim3(blocks), dim3(256), 0, stream>>>(x, c0, c1, c2, out, nTok);
}